// Round 1
// baseline (314.810 us; speedup 1.0000x reference)
//
#include <hip/hip_runtime.h>

#define DD 256
#define NH 8

constexpr float ATT_EPS = 1e-8f;
constexpr float LN_EPS  = 1e-5f;
constexpr float LOG2E   = 1.4426950408889634f;
constexpr float SCALE   = 0.0625f; // 1/sqrt(256)

// Reduce two values across a 256-thread block. All threads get the result.
__device__ __forceinline__ float2 block_reduce2(float a, float b, float* sc, int tid) {
    #pragma unroll
    for (int off = 32; off; off >>= 1) {
        a += __shfl_down(a, off, 64);
        b += __shfl_down(b, off, 64);
    }
    __syncthreads();                       // protect sc from previous use
    if ((tid & 63) == 0) { int w = tid >> 6; sc[2*w] = a; sc[2*w+1] = b; }
    __syncthreads();
    return make_float2(sc[0]+sc[2]+sc[4]+sc[6], sc[1]+sc[3]+sc[5]+sc[7]);
}

template<int LAST>
__global__ __launch_bounds__(256) void flann_layer(
    const float* __restrict__ x_in,     // [B, DD]
    const float* __restrict__ alphas,   // [NH, 3] this layer
    const float* __restrict__ betas,    // [NH, 3]
    const float* __restrict__ g1, const float* __restrict__ b1,   // fla LN
    const float* __restrict__ W,  const float* __restrict__ wb,   // [DD,DD], [DD]
    const float* __restrict__ g2, const float* __restrict__ b2,   // lin LN
    const float* __restrict__ outW, const float* __restrict__ outB,
    float* __restrict__ out)            // [B,DD] or [B] if LAST
{
    __shared__ __align__(16) float xs[DD];
    __shared__ __align__(16) float xln[DD];
    __shared__ float sc[8];
    const int tid  = threadIdx.x;
    const int bidx = blockIdx.x;

    float xv = x_in[bidx * DD + tid];
    xs[tid] = xv;
    __syncthreads();

    const float4* xs4 = reinterpret_cast<const float4*>(xs);

    // ---------------- FLA: thread tid owns output row i = tid, all heads ----
    float acc = 0.f;
    #pragma unroll 1
    for (int h = 0; h < NH; ++h) {
        const float aq = alphas[h*3+0], ak = alphas[h*3+1], av = alphas[h*3+2];
        const float bq = betas [h*3+0], bk = betas [h*3+1], bv = betas [h*3+2];
        // q_j - k_i = aq*x_j + (bq - (ak*x_i + bk))
        const float c = bq - fmaf(ak, xv, bk);

        // pass 1: min_j d_j  (=> max_j s_j), no transcendentals
        float dm0 = 1e38f, dm1 = 1e38f, dm2 = 1e38f, dm3 = 1e38f;
        #pragma unroll 8
        for (int j4 = 0; j4 < DD/4; ++j4) {
            float4 xj = xs4[j4];                       // broadcast ds_read_b128
            dm0 = fminf(dm0, fabsf(fmaf(aq, xj.x, c)));
            dm1 = fminf(dm1, fabsf(fmaf(aq, xj.y, c)));
            dm2 = fminf(dm2, fabsf(fmaf(aq, xj.z, c)));
            dm3 = fminf(dm3, fabsf(fmaf(aq, xj.w, c)));
        }
        const float dmin = fminf(fminf(dm0, dm1), fminf(dm2, dm3));
        const float m = __builtin_amdgcn_rcpf(dmin + ATT_EPS);

        // pass 2: e = exp(s - m); track sum(e) and sum(e*x_j)
        float s0 = 0.f, s1 = 0.f, s2 = 0.f, s3 = 0.f;
        float w0 = 0.f, w1 = 0.f, w2 = 0.f, w3 = 0.f;
        #pragma unroll 4
        for (int j4 = 0; j4 < DD/4; ++j4) {
            float4 xj = xs4[j4];
            float e0 = __builtin_amdgcn_exp2f((__builtin_amdgcn_rcpf(fabsf(fmaf(aq, xj.x, c)) + ATT_EPS) - m) * LOG2E);
            float e1 = __builtin_amdgcn_exp2f((__builtin_amdgcn_rcpf(fabsf(fmaf(aq, xj.y, c)) + ATT_EPS) - m) * LOG2E);
            float e2 = __builtin_amdgcn_exp2f((__builtin_amdgcn_rcpf(fabsf(fmaf(aq, xj.z, c)) + ATT_EPS) - m) * LOG2E);
            float e3 = __builtin_amdgcn_exp2f((__builtin_amdgcn_rcpf(fabsf(fmaf(aq, xj.w, c)) + ATT_EPS) - m) * LOG2E);
            s0 += e0; w0 = fmaf(e0, xj.x, w0);
            s1 += e1; w1 = fmaf(e1, xj.y, w1);
            s2 += e2; w2 = fmaf(e2, xj.z, w2);
            s3 += e3; w3 = fmaf(e3, xj.w, w3);
        }
        const float sum = (s0 + s1) + (s2 + s3);
        const float wx  = (w0 + w1) + (w2 + w3);
        // sum(e*v) = av*wx + bv*sum ; row output = that / sum
        acc += fmaf(av, wx, bv * sum) * __builtin_amdgcn_rcpf(sum);
    }

    // residual + ReLU
    xv = fmaxf(fmaf(SCALE, acc, xv), 0.f);

    // ---------------- LayerNorm 1 ----------------
    float2 r = block_reduce2(xv, xv * xv, sc, tid);
    float mu  = r.x * (1.f / DD);
    float var = r.y * (1.f / DD) - mu * mu;
    float xn  = (xv - mu) * __builtin_amdgcn_rsqf(var + LN_EPS);
    xn = fmaf(xn, g1[tid], b1[tid]);
    xln[tid] = xn;
    __syncthreads();

    // ---------------- Linear: out[c] = sum_d xln[d] * W[d, c] + wb[c] -------
    const float4* xl4 = reinterpret_cast<const float4*>(xln);
    float ga0 = wb[tid], ga1 = 0.f, ga2 = 0.f, ga3 = 0.f;
    #pragma unroll 8
    for (int d4 = 0; d4 < DD/4; ++d4) {
        float4 xd = xl4[d4];                           // broadcast
        ga0 = fmaf(xd.x, W[(4*d4 + 0) * DD + tid], ga0);   // coalesced
        ga1 = fmaf(xd.y, W[(4*d4 + 1) * DD + tid], ga1);
        ga2 = fmaf(xd.z, W[(4*d4 + 2) * DD + tid], ga2);
        ga3 = fmaf(xd.w, W[(4*d4 + 3) * DD + tid], ga3);
    }
    float gv = fmaxf((ga0 + ga1) + (ga2 + ga3), 0.f);

    // ---------------- LayerNorm 2 ----------------
    r = block_reduce2(gv, gv * gv, sc, tid);
    mu  = r.x * (1.f / DD);
    var = r.y * (1.f / DD) - mu * mu;
    float xo = fmaf((gv - mu) * __builtin_amdgcn_rsqf(var + LN_EPS), g2[tid], b2[tid]);

    if (!LAST) {
        out[bidx * DD + tid] = xo;
    } else {
        // final projection: out[b] = sum_d x[d]*outW[d] + outB
        float2 p = block_reduce2(xo * outW[tid], 0.f, sc, tid);
        if (tid == 0) out[bidx] = p.x + outB[0];
    }
}

extern "C" void kernel_launch(void* const* d_in, const int* in_sizes, int n_in,
                              void* d_out, int out_size, void* d_ws, size_t ws_size,
                              hipStream_t stream) {
    const float* x      = (const float*)d_in[0];
    const float* alphas = (const float*)d_in[1];   // [L, NH, 3]
    const float* betas  = (const float*)d_in[2];   // [L, NH, 3]
    const float* flag   = (const float*)d_in[3];   // [L, DD]
    const float* flab   = (const float*)d_in[4];
    const float* linW   = (const float*)d_in[5];   // [L, DD, DD]
    const float* linb   = (const float*)d_in[6];   // [L, DD]
    const float* ling   = (const float*)d_in[7];
    const float* linb2  = (const float*)d_in[8];
    const float* outW   = (const float*)d_in[9];   // [DD]
    const float* outB   = (const float*)d_in[10];  // [1]

    const int B = in_sizes[0] / DD;
    float* ws   = (float*)d_ws;        // [B, DD] intermediate
    float* outp = (float*)d_out;       // [B]

    dim3 grid(B), block(DD);
    // layer 0: x -> ws
    flann_layer<0><<<grid, block, 0, stream>>>(
        x, alphas, betas, flag, flab, linW, linb, ling, linb2,
        nullptr, nullptr, ws);
    // layer 1 (+ fused final projection): ws -> out
    flann_layer<1><<<grid, block, 0, stream>>>(
        ws, alphas + NH*3, betas + NH*3, flag + DD, flab + DD,
        linW + DD*DD, linb + DD, ling + DD, linb2 + DD,
        outW, outB, outp);
}

// Round 2
// 266.790 us; speedup vs baseline: 1.1800x; 1.1800x over previous
//
#include <hip/hip_runtime.h>

#define DD 256
#define NH 8

constexpr float LN_EPS = 1e-5f;
constexpr float LOG2E  = 1.4426950408889634f;
constexpr float SCALE  = 0.0625f; // 1/sqrt(256)

// Reduce two values across a 256-thread block. All threads get the result.
__device__ __forceinline__ float2 block_reduce2(float a, float b, float* sc, int tid) {
    #pragma unroll
    for (int off = 32; off; off >>= 1) {
        a += __shfl_down(a, off, 64);
        b += __shfl_down(b, off, 64);
    }
    __syncthreads();                       // protect sc from previous use
    if ((tid & 63) == 0) { int w = tid >> 6; sc[2*w] = a; sc[2*w+1] = b; }
    __syncthreads();
    return make_float2(sc[0]+sc[2]+sc[4]+sc[6], sc[1]+sc[3]+sc[5]+sc[7]);
}

template<int LAST>
__global__ __launch_bounds__(256, 4) void flann_layer(
    const float* __restrict__ x_in,     // [B, DD]
    const float* __restrict__ alphas,   // [NH, 3] this layer
    const float* __restrict__ betas,    // [NH, 3]
    const float* __restrict__ g1, const float* __restrict__ b1,   // fla LN
    const float* __restrict__ W,  const float* __restrict__ wb,   // [DD,DD], [DD]
    const float* __restrict__ g2, const float* __restrict__ b2,   // lin LN
    const float* __restrict__ outW, const float* __restrict__ outB,
    float* __restrict__ out)            // [B,DD] or [B] if LAST
{
    __shared__ __align__(16) float xs[DD];
    __shared__ __align__(16) float xln[DD];
    __shared__ float sc[8];
    const int tid  = threadIdx.x;
    const int bidx = blockIdx.x;

    float xv = x_in[bidx * DD + tid];
    xs[tid] = xv;
    __syncthreads();

    const float4* xs4 = reinterpret_cast<const float4*>(xs);

    // ---- per-head params (alphas/betas are block-uniform -> SGPRs) ----
    float aqv[NH], avv[NH], bvv[NH], cv[NH], mv[NH], dmn[NH];
    #pragma unroll
    for (int h = 0; h < NH; ++h) {
        const float aq = alphas[h*3+0], ak = alphas[h*3+1];
        const float bq = betas [h*3+0], bk = betas [h*3+1];
        aqv[h] = aq;
        avv[h] = alphas[h*3+2];
        bvv[h] = betas [h*3+2];
        // q_j - k_i = aq*x_j + (bq - (ak*x_i + bk))
        cv[h]  = bq - fmaf(ak, xv, bk);
        dmn[h] = 1e38f;
    }

    // ---- pass 1 (head-fused): dmin per head; fma + min3(abs,abs) ----
    for (int j4 = 0; j4 < DD/4; ++j4) {
        float4 xj = xs4[j4];                        // broadcast ds_read_b128
        #pragma unroll
        for (int h = 0; h < NH; ++h) {
            float d0 = fmaf(aqv[h], xj.x, cv[h]);
            float d1 = fmaf(aqv[h], xj.y, cv[h]);
            float d2 = fmaf(aqv[h], xj.z, cv[h]);
            float d3 = fmaf(aqv[h], xj.w, cv[h]);
            dmn[h] = fminf(dmn[h], fminf(fabsf(d0), fabsf(d1)));  // v_min3
            dmn[h] = fminf(dmn[h], fminf(fabsf(d2), fabsf(d3)));
        }
    }
    #pragma unroll
    for (int h = 0; h < NH; ++h)
        mv[h] = __builtin_amdgcn_rcpf(dmn[h]);      // m = max_j s_j = rcp(min|d|)

    // ---- pass 2 (head-fused): e = exp2((|rcp(d)| - m)*log2e) ----
    // |rcp(d)| == rcp(|d|) exactly (sign symmetry), so abs folds into the
    // subtract as a VOP3 modifier; (r-m) kept as exact sub (Sterbenz) to
    // avoid catastrophic cancellation at large m.
    float sE[NH], sW[NH];
    #pragma unroll
    for (int h = 0; h < NH; ++h) { sE[h] = 0.f; sW[h] = 0.f; }

    for (int j4 = 0; j4 < DD/4; ++j4) {
        float4 xj = xs4[j4];
        #pragma unroll
        for (int h = 0; h < NH; ++h) {
            const float aq = aqv[h], c = cv[h], m = mv[h];
            float d0 = fmaf(aq, xj.x, c);
            float d1 = fmaf(aq, xj.y, c);
            float d2 = fmaf(aq, xj.z, c);
            float d3 = fmaf(aq, xj.w, c);
            float r0 = fabsf(__builtin_amdgcn_rcpf(d0));
            float r1 = fabsf(__builtin_amdgcn_rcpf(d1));
            float r2 = fabsf(__builtin_amdgcn_rcpf(d2));
            float r3 = fabsf(__builtin_amdgcn_rcpf(d3));
            float e0 = __builtin_amdgcn_exp2f((r0 - m) * LOG2E);
            float e1 = __builtin_amdgcn_exp2f((r1 - m) * LOG2E);
            float e2 = __builtin_amdgcn_exp2f((r2 - m) * LOG2E);
            float e3 = __builtin_amdgcn_exp2f((r3 - m) * LOG2E);
            sE[h] += e0; sW[h] = fmaf(e0, xj.x, sW[h]);
            sE[h] += e1; sW[h] = fmaf(e1, xj.y, sW[h]);
            sE[h] += e2; sW[h] = fmaf(e2, xj.z, sW[h]);
            sE[h] += e3; sW[h] = fmaf(e3, xj.w, sW[h]);
        }
    }

    float acc = 0.f;
    #pragma unroll
    for (int h = 0; h < NH; ++h)
        acc += fmaf(avv[h], sW[h], bvv[h] * sE[h]) * __builtin_amdgcn_rcpf(sE[h]);

    // residual + ReLU
    xv = fmaxf(fmaf(SCALE, acc, xv), 0.f);

    // ---------------- LayerNorm 1 ----------------
    float2 r = block_reduce2(xv, xv * xv, sc, tid);
    float mu  = r.x * (1.f / DD);
    float var = r.y * (1.f / DD) - mu * mu;
    float xn  = (xv - mu) * __builtin_amdgcn_rsqf(var + LN_EPS);
    xn = fmaf(xn, g1[tid], b1[tid]);
    xln[tid] = xn;
    __syncthreads();

    // ---------------- Linear: out[c] = sum_d xln[d] * W[d, c] + wb[c] -------
    const float4* xl4 = reinterpret_cast<const float4*>(xln);
    float ga0 = wb[tid], ga1 = 0.f, ga2 = 0.f, ga3 = 0.f;
    #pragma unroll 8
    for (int d4 = 0; d4 < DD/4; ++d4) {
        float4 xd = xl4[d4];                           // broadcast
        ga0 = fmaf(xd.x, W[(4*d4 + 0) * DD + tid], ga0);   // coalesced
        ga1 = fmaf(xd.y, W[(4*d4 + 1) * DD + tid], ga1);
        ga2 = fmaf(xd.z, W[(4*d4 + 2) * DD + tid], ga2);
        ga3 = fmaf(xd.w, W[(4*d4 + 3) * DD + tid], ga3);
    }
    float gv = fmaxf((ga0 + ga1) + (ga2 + ga3), 0.f);

    // ---------------- LayerNorm 2 ----------------
    r = block_reduce2(gv, gv * gv, sc, tid);
    mu  = r.x * (1.f / DD);
    var = r.y * (1.f / DD) - mu * mu;
    float xo = fmaf((gv - mu) * __builtin_amdgcn_rsqf(var + LN_EPS), g2[tid], b2[tid]);

    if (!LAST) {
        out[bidx * DD + tid] = xo;
    } else {
        // final projection: out[b] = sum_d x[d]*outW[d] + outB
        float2 p = block_reduce2(xo * outW[tid], 0.f, sc, tid);
        if (tid == 0) out[bidx] = p.x + outB[0];
    }
}

extern "C" void kernel_launch(void* const* d_in, const int* in_sizes, int n_in,
                              void* d_out, int out_size, void* d_ws, size_t ws_size,
                              hipStream_t stream) {
    const float* x      = (const float*)d_in[0];
    const float* alphas = (const float*)d_in[1];   // [L, NH, 3]
    const float* betas  = (const float*)d_in[2];   // [L, NH, 3]
    const float* flag   = (const float*)d_in[3];   // [L, DD]
    const float* flab   = (const float*)d_in[4];
    const float* linW   = (const float*)d_in[5];   // [L, DD, DD]
    const float* linb   = (const float*)d_in[6];   // [L, DD]
    const float* ling   = (const float*)d_in[7];
    const float* linb2  = (const float*)d_in[8];
    const float* outW   = (const float*)d_in[9];   // [DD]
    const float* outB   = (const float*)d_in[10];  // [1]

    const int B = in_sizes[0] / DD;
    float* ws   = (float*)d_ws;        // [B, DD] intermediate
    float* outp = (float*)d_out;       // [B]

    dim3 grid(B), block(DD);
    // layer 0: x -> ws
    flann_layer<0><<<grid, block, 0, stream>>>(
        x, alphas, betas, flag, flab, linW, linb, ling, linb2,
        nullptr, nullptr, ws);
    // layer 1 (+ fused final projection): ws -> out
    flann_layer<1><<<grid, block, 0, stream>>>(
        ws, alphas + NH*3, betas + NH*3, flag + DD, flab + DD,
        linW + DD*DD, linb + DD, ling + DD, linb2 + DD,
        outW, outB, outp);
}

// Round 3
// 236.871 us; speedup vs baseline: 1.3290x; 1.1263x over previous
//
#include <hip/hip_runtime.h>

#define DD 256
#define NH 8

constexpr float LN_EPS = 1e-5f;
constexpr float SCALE  = 0.0625f; // 1/sqrt(256)
// Schraudolph base-2 exponential constants:
//   e^(r-m) = 2^((r-m)*log2e) ~= bitcast( (uint)( r*A + B ) ),
//   A = 2^23*log2e, B = fma(m, -A, 2^23*(127 - sigma)), sigma = 0.04368 (minimax)
constexpr float A_EXP = 12102203.0f;       // 2^23 * log2(e), rounded
constexpr float B_EXP = 1064986816.0f;     // 2^23 * (127 - 0.0436775...)

// Reduce two values across a 256-thread block. All threads get the result.
__device__ __forceinline__ float2 block_reduce2(float a, float b, float* sc, int tid) {
    #pragma unroll
    for (int off = 32; off; off >>= 1) {
        a += __shfl_down(a, off, 64);
        b += __shfl_down(b, off, 64);
    }
    __syncthreads();                       // protect sc from previous use
    if ((tid & 63) == 0) { int w = tid >> 6; sc[2*w] = a; sc[2*w+1] = b; }
    __syncthreads();
    return make_float2(sc[0]+sc[2]+sc[4]+sc[6], sc[1]+sc[3]+sc[5]+sc[7]);
}

template<int LAST>
__global__ __launch_bounds__(256, 4) void flann_layer(
    const float* __restrict__ x_in,     // [B, DD]
    const float* __restrict__ alphas,   // [NH, 3] this layer
    const float* __restrict__ betas,    // [NH, 3]
    const float* __restrict__ g1, const float* __restrict__ b1,   // fla LN
    const float* __restrict__ W,  const float* __restrict__ wb,   // [DD,DD], [DD]
    const float* __restrict__ g2, const float* __restrict__ b2,   // lin LN
    const float* __restrict__ outW, const float* __restrict__ outB,
    float* __restrict__ out)            // [B,DD] or [B] if LAST
{
    __shared__ __align__(16) float xs[DD];
    __shared__ __align__(16) float xln[DD];
    __shared__ float sc[8];
    const int tid  = threadIdx.x;
    const int bidx = blockIdx.x;

    float xv = x_in[bidx * DD + tid];
    xs[tid] = xv;
    __syncthreads();

    const float4* xs4 = reinterpret_cast<const float4*>(xs);

    // ---- per-head params (alphas/betas are block-uniform -> SGPRs) ----
    float aqv[NH], avv[NH], bvv[NH], cv[NH], Bv[NH], dmn[NH];
    #pragma unroll
    for (int h = 0; h < NH; ++h) {
        const float aq = alphas[h*3+0], ak = alphas[h*3+1];
        const float bq = betas [h*3+0], bk = betas [h*3+1];
        aqv[h] = aq;
        avv[h] = alphas[h*3+2];
        bvv[h] = betas [h*3+2];
        // q_j - k_i = aq*x_j + (bq - (ak*x_i + bk))
        cv[h]  = bq - fmaf(ak, xv, bk);
        dmn[h] = 1e38f;
    }

    // ---- pass 1 (head-fused): dmin per head; fma + min3(abs,abs) ----
    for (int j4 = 0; j4 < DD/4; ++j4) {
        float4 xj = xs4[j4];                        // broadcast ds_read_b128
        #pragma unroll
        for (int h = 0; h < NH; ++h) {
            float d0 = fmaf(aqv[h], xj.x, cv[h]);
            float d1 = fmaf(aqv[h], xj.y, cv[h]);
            float d2 = fmaf(aqv[h], xj.z, cv[h]);
            float d3 = fmaf(aqv[h], xj.w, cv[h]);
            dmn[h] = fminf(dmn[h], fminf(fabsf(d0), fabsf(d1)));  // v_min3
            dmn[h] = fminf(dmn[h], fminf(fabsf(d2), fabsf(d3)));
        }
    }
    // m = max_j s_j = rcp(min|d|); fold (127-sigma)*2^23 - m*A into per-head B.
    // The rounding of m*A is a UNIFORM shift of all softmax args for this
    // (lane, head) -> cancels exactly in the normalized ratio.
    #pragma unroll
    for (int h = 0; h < NH; ++h) {
        float m = __builtin_amdgcn_rcpf(dmn[h]);
        Bv[h] = fmaf(m, -A_EXP, B_EXP);
    }

    // ---- pass 2 (head-fused): e = bits-exp of (r - m) ----
    // r = |rcp(d)| == rcp(|d|) exactly; abs folds into the fma as a modifier.
    float sE[NH], sW[NH];
    #pragma unroll
    for (int h = 0; h < NH; ++h) { sE[h] = 0.f; sW[h] = 0.f; }

    for (int j4 = 0; j4 < DD/4; ++j4) {
        float4 xj = xs4[j4];
        #pragma unroll
        for (int h = 0; h < NH; ++h) {
            const float aq = aqv[h], c = cv[h], Bh = Bv[h];
            float d0 = fmaf(aq, xj.x, c);
            float d1 = fmaf(aq, xj.y, c);
            float d2 = fmaf(aq, xj.z, c);
            float d3 = fmaf(aq, xj.w, c);
            float r0 = fabsf(__builtin_amdgcn_rcpf(d0));
            float r1 = fabsf(__builtin_amdgcn_rcpf(d1));
            float r2 = fabsf(__builtin_amdgcn_rcpf(d2));
            float r3 = fabsf(__builtin_amdgcn_rcpf(d3));
            float e0 = __uint_as_float((unsigned)fmaxf(fmaf(r0, A_EXP, Bh), 0.f));
            float e1 = __uint_as_float((unsigned)fmaxf(fmaf(r1, A_EXP, Bh), 0.f));
            float e2 = __uint_as_float((unsigned)fmaxf(fmaf(r2, A_EXP, Bh), 0.f));
            float e3 = __uint_as_float((unsigned)fmaxf(fmaf(r3, A_EXP, Bh), 0.f));
            sE[h] += e0; sW[h] = fmaf(e0, xj.x, sW[h]);
            sE[h] += e1; sW[h] = fmaf(e1, xj.y, sW[h]);
            sE[h] += e2; sW[h] = fmaf(e2, xj.z, sW[h]);
            sE[h] += e3; sW[h] = fmaf(e3, xj.w, sW[h]);
        }
    }

    float acc = 0.f;
    #pragma unroll
    for (int h = 0; h < NH; ++h)
        acc += fmaf(avv[h], sW[h], bvv[h] * sE[h]) * __builtin_amdgcn_rcpf(sE[h]);

    // residual + ReLU
    xv = fmaxf(fmaf(SCALE, acc, xv), 0.f);

    // ---------------- LayerNorm 1 ----------------
    float2 r = block_reduce2(xv, xv * xv, sc, tid);
    float mu  = r.x * (1.f / DD);
    float var = r.y * (1.f / DD) - mu * mu;
    float xn  = (xv - mu) * __builtin_amdgcn_rsqf(var + LN_EPS);
    xn = fmaf(xn, g1[tid], b1[tid]);
    xln[tid] = xn;
    __syncthreads();

    // ---------------- Linear: out[c] = sum_d xln[d] * W[d, c] + wb[c] -------
    const float4* xl4 = reinterpret_cast<const float4*>(xln);
    float ga0 = wb[tid], ga1 = 0.f, ga2 = 0.f, ga3 = 0.f;
    #pragma unroll 8
    for (int d4 = 0; d4 < DD/4; ++d4) {
        float4 xd = xl4[d4];                           // broadcast
        ga0 = fmaf(xd.x, W[(4*d4 + 0) * DD + tid], ga0);   // coalesced
        ga1 = fmaf(xd.y, W[(4*d4 + 1) * DD + tid], ga1);
        ga2 = fmaf(xd.z, W[(4*d4 + 2) * DD + tid], ga2);
        ga3 = fmaf(xd.w, W[(4*d4 + 3) * DD + tid], ga3);
    }
    float gv = fmaxf((ga0 + ga1) + (ga2 + ga3), 0.f);

    // ---------------- LayerNorm 2 ----------------
    r = block_reduce2(gv, gv * gv, sc, tid);
    mu  = r.x * (1.f / DD);
    var = r.y * (1.f / DD) - mu * mu;
    float xo = fmaf((gv - mu) * __builtin_amdgcn_rsqf(var + LN_EPS), g2[tid], b2[tid]);

    if (!LAST) {
        out[bidx * DD + tid] = xo;
    } else {
        // final projection: out[b] = sum_d x[d]*outW[d] + outB
        float2 p = block_reduce2(xo * outW[tid], 0.f, sc, tid);
        if (tid == 0) out[bidx] = p.x + outB[0];
    }
}

extern "C" void kernel_launch(void* const* d_in, const int* in_sizes, int n_in,
                              void* d_out, int out_size, void* d_ws, size_t ws_size,
                              hipStream_t stream) {
    const float* x      = (const float*)d_in[0];
    const float* alphas = (const float*)d_in[1];   // [L, NH, 3]
    const float* betas  = (const float*)d_in[2];   // [L, NH, 3]
    const float* flag   = (const float*)d_in[3];   // [L, DD]
    const float* flab   = (const float*)d_in[4];
    const float* linW   = (const float*)d_in[5];   // [L, DD, DD]
    const float* linb   = (const float*)d_in[6];   // [L, DD]
    const float* ling   = (const float*)d_in[7];
    const float* linb2  = (const float*)d_in[8];
    const float* outW   = (const float*)d_in[9];   // [DD]
    const float* outB   = (const float*)d_in[10];  // [1]

    const int B = in_sizes[0] / DD;
    float* ws   = (float*)d_ws;        // [B, DD] intermediate
    float* outp = (float*)d_out;       // [B]

    dim3 grid(B), block(DD);
    // layer 0: x -> ws
    flann_layer<0><<<grid, block, 0, stream>>>(
        x, alphas, betas, flag, flab, linW, linb, ling, linb2,
        nullptr, nullptr, ws);
    // layer 1 (+ fused final projection): ws -> out
    flann_layer<1><<<grid, block, 0, stream>>>(
        ws, alphas + NH*3, betas + NH*3, flag + DD, flab + DD,
        linW + DD*DD, linb + DD, ling + DD, linb2 + DD,
        outW, outB, outp);
}

// Round 4
// 210.711 us; speedup vs baseline: 1.4940x; 1.1242x over previous
//
#include <hip/hip_runtime.h>

#define DD 256
#define NH 8

constexpr float LN_EPS = 1e-5f;
constexpr float SCALE  = 0.0625f; // 1/sqrt(256)
// Schraudolph base-2 exponential: e^(r-m) ~= bitcast((uint)(r*A + B(m)))
constexpr float A_EXP  = 12102203.0f;       // 2^23 * log2(e)
constexpr float B_EXP  = 1064986816.0f;     // 2^23 * (127 - 0.0436775)
#define RCP_MAGIC 0x7EF311C3u

// r ~= 1/|d| : magic seed + 1 Newton step. Rel err <= ~1.2e-3, undershoots.
// The seed's sign bit is garbage when d<0 (wraps through the subtract) --
// absorbed by free VOP3 abs() modifiers on the consumers. 3 VALU ops total.
__device__ __forceinline__ float rcp_abs_nr(float d) {
    float y = __uint_as_float(RCP_MAGIC - __float_as_uint(d));
    return fabsf(y) * fmaf(-fabsf(d), fabsf(y), 2.0f);
}

// weight = bitcast((uint)(r*A + Bh)); v_cvt_u32_f32 saturates neg/NaN -> 0,
// which implements exp underflow exactly. asm because the C cast is UB.
__device__ __forceinline__ float wexp(float r, float Bh) {
    float f = fmaf(r, A_EXP, Bh);
    unsigned u;
    asm("v_cvt_u32_f32 %0, %1" : "=v"(u) : "v"(f));
    return __uint_as_float(u);
}

// Reduce two values across a 256-thread block. All threads get the result.
__device__ __forceinline__ float2 block_reduce2(float a, float b, float* sc, int tid) {
    #pragma unroll
    for (int off = 32; off; off >>= 1) {
        a += __shfl_down(a, off, 64);
        b += __shfl_down(b, off, 64);
    }
    __syncthreads();                       // protect sc from previous use
    if ((tid & 63) == 0) { int w = tid >> 6; sc[2*w] = a; sc[2*w+1] = b; }
    __syncthreads();
    return make_float2(sc[0]+sc[2]+sc[4]+sc[6], sc[1]+sc[3]+sc[5]+sc[7]);
}

template<int LAST>
__global__ __launch_bounds__(256, 4) void flann_layer(
    const float* __restrict__ x_in,     // [B, DD]
    const float* __restrict__ alphas,   // [NH, 3] this layer
    const float* __restrict__ betas,    // [NH, 3]
    const float* __restrict__ g1, const float* __restrict__ b1,   // fla LN
    const float* __restrict__ W,  const float* __restrict__ wb,   // [DD,DD], [DD]
    const float* __restrict__ g2, const float* __restrict__ b2,   // lin LN
    const float* __restrict__ outW, const float* __restrict__ outB,
    float* __restrict__ out)            // [B,DD] or [B] if LAST
{
    __shared__ __align__(16) float xs[DD];
    __shared__ __align__(16) float xln[DD];
    __shared__ float sc[8];
    const int tid  = threadIdx.x;
    const int bidx = blockIdx.x;

    float xv = x_in[bidx * DD + tid];
    xs[tid] = xv;
    __syncthreads();

    const float4* xs4 = reinterpret_cast<const float4*>(xs);

    // ---- per-head params (alphas/betas are block-uniform -> SGPRs) ----
    float aqv[NH], avv[NH], bvv[NH], cv[NH], Bv[NH], dmn[NH];
    #pragma unroll
    for (int h = 0; h < NH; ++h) {
        const float aq = alphas[h*3+0], ak = alphas[h*3+1];
        const float bq = betas [h*3+0], bk = betas [h*3+1];
        aqv[h] = aq;
        avv[h] = alphas[h*3+2];
        bvv[h] = betas [h*3+2];
        // q_j - k_i = aq*x_j + (bq - (ak*x_i + bk))
        cv[h]  = bq - fmaf(ak, xv, bk);
        dmn[h] = 1e38f;
    }

    // ---- pass 1 (head-fused): dmin per head; fma + min3(abs,abs) ----
    #pragma unroll 4
    for (int j4 = 0; j4 < DD/4; ++j4) {
        float4 xj = xs4[j4];                        // broadcast ds_read_b128
        #pragma unroll
        for (int h = 0; h < NH; ++h) {
            float d0 = fmaf(aqv[h], xj.x, cv[h]);
            float d1 = fmaf(aqv[h], xj.y, cv[h]);
            float d2 = fmaf(aqv[h], xj.z, cv[h]);
            float d3 = fmaf(aqv[h], xj.w, cv[h]);
            dmn[h] = fminf(dmn[h], fminf(fabsf(d0), fabsf(d1)));  // v_min3
            dmn[h] = fminf(dmn[h], fminf(fabsf(d2), fabsf(d3)));
        }
    }
    // m = rcp_abs_nr(dmin) -- MUST use the same approximation as pass 2 so
    // the argmin element reproduces r == m bitwise (top weight = 2^-sigma).
    // An exact-rcp m would exceed every NR-undershot r by delta*m; at large m
    // that flushes ALL weights to zero -> 0/0.
    #pragma unroll
    for (int h = 0; h < NH; ++h)
        Bv[h] = fmaf(rcp_abs_nr(dmn[h]), -A_EXP, B_EXP);

    // ---- pass 2 (head-fused): e = bits-exp of (r - m), r = 1/|d| ----
    float sE[NH], sW[NH];
    #pragma unroll
    for (int h = 0; h < NH; ++h) { sE[h] = 0.f; sW[h] = 0.f; }

    #pragma unroll 4
    for (int j4 = 0; j4 < DD/4; ++j4) {
        float4 xj = xs4[j4];
        #pragma unroll
        for (int h = 0; h < NH; ++h) {
            const float aq = aqv[h], c = cv[h], Bh = Bv[h];
            float d0 = fmaf(aq, xj.x, c);
            float d1 = fmaf(aq, xj.y, c);
            float d2 = fmaf(aq, xj.z, c);
            float d3 = fmaf(aq, xj.w, c);
            float e0 = wexp(rcp_abs_nr(d0), Bh);
            float e1 = wexp(rcp_abs_nr(d1), Bh);
            float e2 = wexp(rcp_abs_nr(d2), Bh);
            float e3 = wexp(rcp_abs_nr(d3), Bh);
            sE[h] += e0; sW[h] = fmaf(e0, xj.x, sW[h]);
            sE[h] += e1; sW[h] = fmaf(e1, xj.y, sW[h]);
            sE[h] += e2; sW[h] = fmaf(e2, xj.z, sW[h]);
            sE[h] += e3; sW[h] = fmaf(e3, xj.w, sW[h]);
        }
    }

    float acc = 0.f;
    #pragma unroll
    for (int h = 0; h < NH; ++h)
        acc += fmaf(avv[h], sW[h], bvv[h] * sE[h]) * __builtin_amdgcn_rcpf(sE[h]);

    // residual + ReLU
    xv = fmaxf(fmaf(SCALE, acc, xv), 0.f);

    // ---------------- LayerNorm 1 ----------------
    float2 r = block_reduce2(xv, xv * xv, sc, tid);
    float mu  = r.x * (1.f / DD);
    float var = r.y * (1.f / DD) - mu * mu;
    float xn  = (xv - mu) * __builtin_amdgcn_rsqf(var + LN_EPS);
    xn = fmaf(xn, g1[tid], b1[tid]);
    xln[tid] = xn;
    __syncthreads();

    // ---------------- Linear: out[c] = sum_d xln[d] * W[d, c] + wb[c] -------
    const float4* xl4 = reinterpret_cast<const float4*>(xln);
    float ga0 = wb[tid], ga1 = 0.f, ga2 = 0.f, ga3 = 0.f;
    #pragma unroll 8
    for (int d4 = 0; d4 < DD/4; ++d4) {
        float4 xd = xl4[d4];                           // broadcast
        ga0 = fmaf(xd.x, W[(4*d4 + 0) * DD + tid], ga0);   // coalesced
        ga1 = fmaf(xd.y, W[(4*d4 + 1) * DD + tid], ga1);
        ga2 = fmaf(xd.z, W[(4*d4 + 2) * DD + tid], ga2);
        ga3 = fmaf(xd.w, W[(4*d4 + 3) * DD + tid], ga3);
    }
    float gv = fmaxf((ga0 + ga1) + (ga2 + ga3), 0.f);

    // ---------------- LayerNorm 2 ----------------
    r = block_reduce2(gv, gv * gv, sc, tid);
    mu  = r.x * (1.f / DD);
    var = r.y * (1.f / DD) - mu * mu;
    float xo = fmaf((gv - mu) * __builtin_amdgcn_rsqf(var + LN_EPS), g2[tid], b2[tid]);

    if (!LAST) {
        out[bidx * DD + tid] = xo;
    } else {
        // final projection: out[b] = sum_d x[d]*outW[d] + outB
        float2 p = block_reduce2(xo * outW[tid], 0.f, sc, tid);
        if (tid == 0) out[bidx] = p.x + outB[0];
    }
}

extern "C" void kernel_launch(void* const* d_in, const int* in_sizes, int n_in,
                              void* d_out, int out_size, void* d_ws, size_t ws_size,
                              hipStream_t stream) {
    const float* x      = (const float*)d_in[0];
    const float* alphas = (const float*)d_in[1];   // [L, NH, 3]
    const float* betas  = (const float*)d_in[2];   // [L, NH, 3]
    const float* flag   = (const float*)d_in[3];   // [L, DD]
    const float* flab   = (const float*)d_in[4];
    const float* linW   = (const float*)d_in[5];   // [L, DD, DD]
    const float* linb   = (const float*)d_in[6];   // [L, DD]
    const float* ling   = (const float*)d_in[7];
    const float* linb2  = (const float*)d_in[8];
    const float* outW   = (const float*)d_in[9];   // [DD]
    const float* outB   = (const float*)d_in[10];  // [1]

    const int B = in_sizes[0] / DD;
    float* ws   = (float*)d_ws;        // [B, DD] intermediate
    float* outp = (float*)d_out;       // [B]

    dim3 grid(B), block(DD);
    // layer 0: x -> ws
    flann_layer<0><<<grid, block, 0, stream>>>(
        x, alphas, betas, flag, flab, linW, linb, ling, linb2,
        nullptr, nullptr, ws);
    // layer 1 (+ fused final projection): ws -> out
    flann_layer<1><<<grid, block, 0, stream>>>(
        ws, alphas + NH*3, betas + NH*3, flag + DD, flab + DD,
        linW + DD*DD, linb + DD, ling + DD, linb2 + DD,
        outW, outB, outp);
}

// Round 5
// 187.433 us; speedup vs baseline: 1.6796x; 1.1242x over previous
//
#include <hip/hip_runtime.h>

#define DD 256
#define NH 8

constexpr float LN_EPS = 1e-5f;
constexpr float SCALE  = 0.0625f;         // 1/sqrt(256)
// Scaled-Schraudolph: store x_hat = x * KS (KS = ln2/2^23) so that
// 1/|d_hat| = 2^23*log2(e)/|d| is DIRECTLY the exp bit-argument; the NR
// product then fuses with the bias add in one fma (single rounding).
constexpr float KS     = 8.2629579e-8f;   // ln2 / 2^23
constexpr float A_EXP  = 12102203.0f;     // 2^23 * log2(e) = 1/KS (sW rescale)
constexpr float B_EXP  = 1064986816.0f;   // 2^23 * (127 - 0.0436775)
#define RCP_MAGIC 0x7EF311C3u

// f = |y|*w + Bh  (NR product fused with bias, exact internal product);
// v_cvt_u32_f32 saturates neg/NaN -> 0 = exp underflow. asm: C cast is UB.
__device__ __forceinline__ float wexp_ys(float yabs, float w, float Bh) {
    float f = fmaf(yabs, w, Bh);
    unsigned u;
    asm("v_cvt_u32_f32 %0, %1" : "=v"(u) : "v"(f));
    return __uint_as_float(u);
}

// Reduce two values across a 512-thread block (8 waves). All threads get it.
__device__ __forceinline__ float2 block_reduce2(float a, float b, float* sc, int tid) {
    #pragma unroll
    for (int off = 32; off; off >>= 1) {
        a += __shfl_down(a, off, 64);
        b += __shfl_down(b, off, 64);
    }
    __syncthreads();                       // protect sc from previous use
    if ((tid & 63) == 0) { int w = tid >> 6; sc[2*w] = a; sc[2*w+1] = b; }
    __syncthreads();
    float ra = 0.f, rb = 0.f;
    #pragma unroll
    for (int w = 0; w < 8; ++w) { ra += sc[2*w]; rb += sc[2*w+1]; }
    return make_float2(ra, rb);
}

template<int LAST>
__global__ __launch_bounds__(512, 8) void flann_layer(
    const float* __restrict__ x_in,     // [B, DD]
    const float* __restrict__ alphas,   // [NH, 3] this layer
    const float* __restrict__ betas,    // [NH, 3]
    const float* __restrict__ g1, const float* __restrict__ b1,   // fla LN
    const float* __restrict__ W,  const float* __restrict__ wb,   // [DD,DD], [DD]
    const float* __restrict__ g2, const float* __restrict__ b2,   // lin LN
    const float* __restrict__ outW, const float* __restrict__ outB,
    float* __restrict__ out)            // [B,DD] or [B] if LAST
{
    __shared__ __align__(16) float xs[DD];          // x * KS
    __shared__ __align__(16) float xln[DD];
    __shared__ float combE[2][NH][DD];              // dmn, then sE, then GEMM
    __shared__ float combW[2][NH][DD];              // sW partials
    __shared__ float sc[16];

    const int tid  = threadIdx.x;
    const int i    = tid & (DD - 1);    // feature row this thread owns
    const int half = tid >> 8;          // which half of the j-range
    const int bidx = blockIdx.x;

    float xv = x_in[bidx * DD + i];
    if (half == 0) xs[i] = xv * KS;
    __syncthreads();

    const float4* xs4 = reinterpret_cast<const float4*>(xs);
    const int jb = half * (DD / 8);     // 32 float4-groups per half

    // ---- per-head params (alphas/betas uniform -> SGPRs) ----
    float aqv[NH], cv[NH], dmn[NH], Bv[NH];
    #pragma unroll
    for (int h = 0; h < NH; ++h) {
        const float aq = alphas[h*3+0], ak = alphas[h*3+1];
        const float bq = betas [h*3+0], bk = betas [h*3+1];
        aqv[h] = aq;
        cv[h]  = (bq - fmaf(ak, xv, bk)) * KS;   // scaled c
        dmn[h] = 1e38f;
    }

    // ---- pass 1: dmin per head over OWN half of j ----
    #pragma unroll 4
    for (int j4 = 0; j4 < DD/8; ++j4) {
        float4 xj = xs4[jb + j4];
        #pragma unroll
        for (int h = 0; h < NH; ++h) {
            float d0 = fmaf(aqv[h], xj.x, cv[h]);
            float d1 = fmaf(aqv[h], xj.y, cv[h]);
            float d2 = fmaf(aqv[h], xj.z, cv[h]);
            float d3 = fmaf(aqv[h], xj.w, cv[h]);
            dmn[h] = fminf(dmn[h], fminf(fabsf(d0), fabsf(d1)));  // v_min3
            dmn[h] = fminf(dmn[h], fminf(fabsf(d2), fabsf(d3)));
        }
    }
    #pragma unroll
    for (int h = 0; h < NH; ++h) combE[half][h][i] = dmn[h];
    __syncthreads();
    // combine halves; Bh = B_EXP - m, m via the SAME seed+NR chain as pass 2
    // (bit-identical for the argmin element; seed of -x differs from seed of
    //  x only in the top bit, so |y| matches exactly).
    #pragma unroll
    for (int h = 0; h < NH; ++h) {
        float dm = fminf(dmn[h], combE[half ^ 1][h][i]);
        float y  = __uint_as_float(RCP_MAGIC - __float_as_uint(dm));
        float w  = fmaf(-dm, fabsf(y), 2.0f);
        Bv[h]    = B_EXP - fabsf(y) * w;
    }
    __syncthreads();    // all dmn reads done before combE is reused

    // ---- pass 2: e = bits(cvt(|y|*w + Bh)) over OWN half of j ----
    float sE[NH], sW[NH];
    #pragma unroll
    for (int h = 0; h < NH; ++h) { sE[h] = 0.f; sW[h] = 0.f; }

    #pragma unroll 4
    for (int j4 = 0; j4 < DD/8; ++j4) {
        float4 xj = xs4[jb + j4];
        #pragma unroll
        for (int h = 0; h < NH; ++h) {
            const float aq = aqv[h], c = cv[h], Bh = Bv[h];
            float dh0 = fmaf(aq, xj.x, c);
            float dh1 = fmaf(aq, xj.y, c);
            float dh2 = fmaf(aq, xj.z, c);
            float dh3 = fmaf(aq, xj.w, c);
            float y0 = __uint_as_float(RCP_MAGIC - __float_as_uint(dh0));
            float y1 = __uint_as_float(RCP_MAGIC - __float_as_uint(dh1));
            float y2 = __uint_as_float(RCP_MAGIC - __float_as_uint(dh2));
            float y3 = __uint_as_float(RCP_MAGIC - __float_as_uint(dh3));
            float w0 = fmaf(-fabsf(dh0), fabsf(y0), 2.0f);
            float w1 = fmaf(-fabsf(dh1), fabsf(y1), 2.0f);
            float w2 = fmaf(-fabsf(dh2), fabsf(y2), 2.0f);
            float w3 = fmaf(-fabsf(dh3), fabsf(y3), 2.0f);
            float e0 = wexp_ys(fabsf(y0), w0, Bh);
            float e1 = wexp_ys(fabsf(y1), w1, Bh);
            float e2 = wexp_ys(fabsf(y2), w2, Bh);
            float e3 = wexp_ys(fabsf(y3), w3, Bh);
            sE[h] += e0; sW[h] = fmaf(e0, xj.x, sW[h]);
            sE[h] += e1; sW[h] = fmaf(e1, xj.y, sW[h]);
            sE[h] += e2; sW[h] = fmaf(e2, xj.z, sW[h]);
            sE[h] += e3; sW[h] = fmaf(e3, xj.w, sW[h]);
        }
    }
    #pragma unroll
    for (int h = 0; h < NH; ++h) { combE[half][h][i] = sE[h]; combW[half][h][i] = sW[h]; }
    __syncthreads();

    // ---- combine halves, head accumulate, residual + ReLU (half 0 only) ----
    float xr = 0.f;
    if (half == 0) {
        float acc = 0.f;
        #pragma unroll
        for (int h = 0; h < NH; ++h) {
            const float av = alphas[h*3+2], bv = betas[h*3+2];
            float sEt = sE[h] + combE[1][h][i];
            float sWt = (sW[h] + combW[1][h][i]) * A_EXP;   // undo KS scale
            acc += fmaf(av, sWt, bv * sEt) * __builtin_amdgcn_rcpf(sEt);
        }
        xr = fmaxf(fmaf(SCALE, acc, xv), 0.f);
    }

    // ---------------- LayerNorm 1 (half-1 contributes zeros) ----------------
    float2 r = block_reduce2(xr, xr * xr, sc, tid);
    float mu  = r.x * (1.f / DD);
    float var = r.y * (1.f / DD) - mu * mu;
    if (half == 0) {
        float xn = (xr - mu) * __builtin_amdgcn_rsqf(var + LN_EPS);
        xln[i] = fmaf(xn, g1[i], b1[i]);
    }
    __syncthreads();

    // ---------------- Linear: split d-range across halves -------------------
    const float4* xl4 = reinterpret_cast<const float4*>(xln);
    float ga0 = (half == 0) ? wb[i] : 0.f, ga1 = 0.f, ga2 = 0.f, ga3 = 0.f;
    #pragma unroll 8
    for (int d4 = 0; d4 < DD/8; ++d4) {
        float4 xd = xl4[jb + d4];
        int dr = 4 * (jb + d4);
        ga0 = fmaf(xd.x, W[(dr + 0) * DD + i], ga0);   // coalesced in i
        ga1 = fmaf(xd.y, W[(dr + 1) * DD + i], ga1);
        ga2 = fmaf(xd.z, W[(dr + 2) * DD + i], ga2);
        ga3 = fmaf(xd.w, W[(dr + 3) * DD + i], ga3);
    }
    combE[half][0][i] = (ga0 + ga1) + (ga2 + ga3);
    __syncthreads();

    float gv = 0.f;
    if (half == 0) gv = fmaxf(combE[0][0][i] + combE[1][0][i], 0.f);

    // ---------------- LayerNorm 2 ----------------
    r = block_reduce2(gv, gv * gv, sc, tid);
    mu  = r.x * (1.f / DD);
    var = r.y * (1.f / DD) - mu * mu;
    float xo = 0.f;
    if (half == 0)
        xo = fmaf((gv - mu) * __builtin_amdgcn_rsqf(var + LN_EPS), g2[i], b2[i]);

    if (!LAST) {
        if (half == 0) out[bidx * DD + i] = xo;
    } else {
        float pr = (half == 0) ? xo * outW[i] : 0.f;
        float2 p = block_reduce2(pr, 0.f, sc, tid);
        if (tid == 0) out[bidx] = p.x + outB[0];
    }
}

extern "C" void kernel_launch(void* const* d_in, const int* in_sizes, int n_in,
                              void* d_out, int out_size, void* d_ws, size_t ws_size,
                              hipStream_t stream) {
    const float* x      = (const float*)d_in[0];
    const float* alphas = (const float*)d_in[1];   // [L, NH, 3]
    const float* betas  = (const float*)d_in[2];   // [L, NH, 3]
    const float* flag   = (const float*)d_in[3];   // [L, DD]
    const float* flab   = (const float*)d_in[4];
    const float* linW   = (const float*)d_in[5];   // [L, DD, DD]
    const float* linb   = (const float*)d_in[6];   // [L, DD]
    const float* ling   = (const float*)d_in[7];
    const float* linb2  = (const float*)d_in[8];
    const float* outW   = (const float*)d_in[9];   // [DD]
    const float* outB   = (const float*)d_in[10];  // [1]

    const int B = in_sizes[0] / DD;
    float* ws   = (float*)d_ws;        // [B, DD] intermediate
    float* outp = (float*)d_out;       // [B]

    dim3 grid(B), block(512);
    // layer 0: x -> ws
    flann_layer<0><<<grid, block, 0, stream>>>(
        x, alphas, betas, flag, flab, linW, linb, ling, linb2,
        nullptr, nullptr, ws);
    // layer 1 (+ fused final projection): ws -> out
    flann_layer<1><<<grid, block, 0, stream>>>(
        ws, alphas + NH*3, betas + NH*3, flag + DD, flab + DD,
        linW + DD*DD, linb + DD, ling + DD, linb2 + DD,
        outW, outB, outp);
}